// Round 6
// baseline (588.992 us; speedup 1.0000x reference)
//
#include <hip/hip_runtime.h>
#include <cstddef>

// Problem constants (match reference)
constexpr int B = 64, T = 1024, I = 8, H = 512, O = 2;
constexpr float ALPHA = 0.2f;
constexpr float NOISE_STD = 0.05f;

// Ring depth for the noise software pipeline (float2 per lane per step).
constexpr int PF = 8;

// ---------------------------------------------------------------------------
// DPP wave-64 sum reduction: result (total of all 64 lanes) lands in lane 63.
// ---------------------------------------------------------------------------
template <int CTRL>
__device__ __forceinline__ float dpp_add(float x) {
    int y = __builtin_amdgcn_update_dpp(0, __float_as_int(x), CTRL, 0xF, 0xF, true);
    return x + __int_as_float(y);
}

__device__ __forceinline__ float wave_sum_to_lane63(float x) {
    x = dpp_add<0x111>(x);  // row_shr:1
    x = dpp_add<0x112>(x);  // row_shr:2
    x = dpp_add<0x114>(x);  // row_shr:4
    x = dpp_add<0x118>(x);  // row_shr:8   -> lane 15 of each row = row sum
    x = dpp_add<0x142>(x);  // row_bcast:15
    x = dpp_add<0x143>(x);  // row_bcast:31 -> lane 63 = full sum
    return x;
}

// Fast tanh: 1 - 2/(exp(2x)+1), via v_exp_f32 + v_rcp_f32.
__device__ __forceinline__ float fast_tanh(float x) {
    float z = __builtin_amdgcn_exp2f(x * 2.885390081777927f);  // e^(2x)
    return fmaf(-2.0f, __builtin_amdgcn_rcpf(z + 1.0f), 1.0f);
}

// ---------------------------------------------------------------------------
// Fully fused RNN: one 256-thread block per batch, 4 waves, wave w owns
// hidden units [w*128, w*128+128), lane l owns units j0 = w*128+2l, j0+1.
//
// R6 change (ONE theory): STORE-SOURCE REGISTER HAZARD. A VMEM store holds
// its data VGPRs until vmcnt retires it; the compiler must s_waitcnt before
// REDEFINING them. h[] is stored to traj at step t and redefined at t+1
// (~200 cyc later), but store retirement under streaming is ~300-600 cyc —
// a ~400-500 cyc scalar stall EVERY step, in every variant since R1, and
// untouched by load-side hygiene (R5 A/B proved loads are not the issue).
// Fix: rotating stash rings give each store's source registers a 2-4 step
// lifetime (opaque asm defeats copy-propagation back to h[]), so the
// pre-redefinition wait is satisfied long before it's needed.
//
// Everything else identical to R5 (raw lgkm-only barrier, unconditional
// clamped ring refill, fused input projection + output trees).
// ---------------------------------------------------------------------------
__global__ __launch_bounds__(256)
void rnn_fused4_kernel(const float* __restrict__ input,
                       const float* __restrict__ noise,
                       const float* __restrict__ wi,
                       const float* __restrict__ si,
                       const float* __restrict__ m,
                       const float* __restrict__ n,
                       const float* __restrict__ wo,
                       const float* __restrict__ so,
                       const float* __restrict__ h0,
                       float* __restrict__ out,    // (B,T,O)
                       float* __restrict__ traj)   // (B,T,H)
{
    const int b    = blockIdx.x;
    const int w    = threadIdx.x >> 6;
    const int lane = threadIdx.x & 63;
    const int j0   = w * 128 + 2 * lane;   // first of this lane's 2 units

    __shared__ float  xin[T * I];          // 32 KB: input[b], staged once
    __shared__ float4 part[2][4];          // [t&1][wave] = (pa0,pa1,po0,po1)

    // ---- stage input[b] into LDS (coalesced float4) ----
    {
        const float4* src = (const float4*)(input + (size_t)b * T * I);
        float4*       dst = (float4*)xin;
#pragma unroll
        for (int i = 0; i < (T * I / 4) / 256; ++i)
            dst[threadIdx.x + 256 * i] = src[threadIdx.x + 256 * i];
    }
    __syncthreads();   // once, outside the hot loop — vmcnt drain is fine here

    constexpr float RS  = ALPHA / (float)H;
    constexpr float OMA = 1.0f - ALPHA;
    const float so0 = so[0] / (float)H;
    const float so1 = so[1] / (float)H;

    // per-lane coefficients for 2 adjacent units (rows 2j0..2j0+3, 16B aligned)
    const float4 mv = *(const float4*)(m + 2 * j0);
    const float4 nv = *(const float4*)(n + 2 * j0);
    const float4 wv = *(const float4*)(wo + 2 * j0);
    const float mm0[2] = {mv.x * RS, mv.z * RS};
    const float mm1[2] = {mv.y * RS, mv.w * RS};
    const float nn0[2] = {nv.x, nv.z};
    const float nn1[2] = {nv.y, nv.w};
    const float ww0[2] = {wv.x, wv.z};
    const float ww1[2] = {wv.y, wv.w};

    float wif[I][2];
#pragma unroll
    for (int i = 0; i < I; ++i) {
        wif[i][0] = wi[i * H + j0]     * si[i];
        wif[i][1] = wi[i * H + j0 + 1] * si[i];
    }

    const float2 h0v = *(const float2*)(h0 + j0);
    float h[2] = {h0v.x, h0v.y};
    float r[2] = {tanhf(h[0]), tanhf(h[1])};   // full precision, once

    const float* pn   = noise + (size_t)b * T * H + j0;
    float*       pt   = traj  + (size_t)b * T * H + j0;
    float*       pout = out   + (size_t)b * T * O;

    // ---- fill the PF-deep noise register ring (statically indexed) ----
    float2 ring[PF];
#pragma unroll
    for (int u = 0; u < PF; ++u) ring[u] = *(const float2*)(pn + (size_t)u * H);

    // ---- store-source stash rings (live across iterations) ----
    float2 hst[4];   // traj store sources: 4-step register lifetime
    float2 ost[2];   // out  store sources: 2-step register lifetime

    static_assert(T % PF == 0, "T must be a multiple of PF");

    for (int tb = 0; tb < T; tb += PF) {
#pragma unroll
        for (int u = 0; u < PF; ++u) {
            const int t  = tb + u;
            // clamped refill index: uniform s_cselect, NO branch
            const int tn = (t + PF < T) ? (t + PF) : (T - 1);

            // uniform broadcast read of this step's 8 input values
            const float4 xa = *(const float4*)(xin + t * I);
            const float4 xb = *(const float4*)(xin + t * I + 4);

            // rank-2 + output partials from current r (4 independent 2-fma chains)
            float pa0 = fmaf(r[1], nn0[1], r[0] * nn0[0]);
            float pa1 = fmaf(r[1], nn1[1], r[0] * nn1[0]);
            float po0 = fmaf(r[1], ww0[1], r[0] * ww0[0]);
            float po1 = fmaf(r[1], ww1[1], r[0] * ww1[0]);

            // consume ring slot u, UNCONDITIONALLY refill with step tn
            const float2 nz = ring[u];
            ring[u] = *(const float2*)(pn + (size_t)tn * H);

            // 4 interleaved DPP trees (independent -> latency overlaps)
            pa0 = wave_sum_to_lane63(pa0);
            pa1 = wave_sum_to_lane63(pa1);
            po0 = wave_sum_to_lane63(po0);
            po1 = wave_sum_to_lane63(po1);

            // d + (1-a)h, off the post-barrier critical path
            const float x0 = xa.x, x1 = xa.y, x2 = xa.z, x3 = xa.w;
            const float x4 = xb.x, x5 = xb.y, x6 = xb.z, x7 = xb.w;
            float acc0 = x0 * wif[0][0], acc1 = x0 * wif[0][1];
            acc0 = fmaf(x1, wif[1][0], acc0); acc1 = fmaf(x1, wif[1][1], acc1);
            acc0 = fmaf(x2, wif[2][0], acc0); acc1 = fmaf(x2, wif[2][1], acc1);
            acc0 = fmaf(x3, wif[3][0], acc0); acc1 = fmaf(x3, wif[3][1], acc1);
            acc0 = fmaf(x4, wif[4][0], acc0); acc1 = fmaf(x4, wif[4][1], acc1);
            acc0 = fmaf(x5, wif[5][0], acc0); acc1 = fmaf(x5, wif[5][1], acc1);
            acc0 = fmaf(x6, wif[6][0], acc0); acc1 = fmaf(x6, wif[6][1], acc1);
            acc0 = fmaf(x7, wif[7][0], acc0); acc1 = fmaf(x7, wif[7][1], acc1);
            const float dv0 = fmaf(NOISE_STD, nz.x, ALPHA * acc0);
            const float dv1 = fmaf(NOISE_STD, nz.y, ALPHA * acc1);
            const float pre0 = fmaf(h[0], OMA, dv0);
            const float pre1 = fmaf(h[1], OMA, dv1);

            if (lane == 63) part[t & 1][w] = make_float4(pa0, pa1, po0, po1);

            // raw barrier: LDS-visibility wait ONLY (no vmcnt drain)
            __builtin_amdgcn_sched_barrier(0);
            asm volatile("s_waitcnt lgkmcnt(0)" ::: "memory");
            __builtin_amdgcn_s_barrier();
            __builtin_amdgcn_sched_barrier(0);

            // broadcast-read the 4 wave partials
            const float4 q0 = part[t & 1][0];
            const float4 q1 = part[t & 1][1];
            const float4 q2 = part[t & 1][2];
            const float4 q3 = part[t & 1][3];
            const float a0 = (q0.x + q1.x) + (q2.x + q3.x);
            const float a1 = (q0.y + q1.y) + (q2.y + q3.y);

            // out[t-1] (pre-update r), branchless wrap; store source goes
            // through a 2-deep stash ring so its regs live 2 steps.
            if (lane == 63) {
                const float o0 = (q0.z + q1.z) + (q2.z + q3.z);
                const float o1 = (q0.w + q1.w) + (q2.w + q3.w);
                ost[u & 1] = make_float2(o0 * so0, o1 * so1);
                asm volatile("" : "+v"(ost[u & 1].x), "+v"(ost[u & 1].y));
                const int tm1 = (t + T - 1) & (T - 1);
                *(float2*)(pout + (size_t)tm1 * O) = ost[u & 1];
            }

            // state update + fast tanh (critical path: 2 fma + tanh)
            h[0] = fmaf(a1, mm1[0], fmaf(a0, mm0[0], pre0));
            h[1] = fmaf(a1, mm1[1], fmaf(a0, mm0[1], pre1));
            r[0] = fast_tanh(h[0]);
            r[1] = fast_tanh(h[1]);

            // traj store via 4-deep stash ring: the store's source regs are
            // not redefined for 4 steps, so the compiler's pre-redefinition
            // vmcnt wait is satisfied long before it's needed. The opaque
            // asm blocks copy-propagation back to h[] (which IS redefined
            // next step and would reintroduce the per-step stall).
            hst[u & 3] = make_float2(h[0], h[1]);
            asm volatile("" : "+v"(hst[u & 3].x), "+v"(hst[u & 3].y));
            *(float2*)(pt + (size_t)t * H) = hst[u & 3];
        }
    }

    // ---- final output for t = T-1 (uses post-update r) ----
    {
        float po0 = fmaf(r[1], ww0[1], r[0] * ww0[0]);
        float po1 = fmaf(r[1], ww1[1], r[0] * ww1[0]);
        po0 = wave_sum_to_lane63(po0);
        po1 = wave_sum_to_lane63(po1);
        // Safe to reuse part[0]: every in-loop read of part[0] (last at
        // t=T-2) completed before barrier(T-1), which precedes this write.
        if (lane == 63) part[0][w] = make_float4(po0, po1, 0.f, 0.f);
        __syncthreads();
        // lane63 of EVERY wave stores the final value: each wave's stale
        // t=0 wrap-store to out[T-1] is ordered before this one (same wave,
        // same address), so the last writer globally is a correct store.
        if (lane == 63) {
            const float4 q0 = part[0][0];
            const float4 q1 = part[0][1];
            const float4 q2 = part[0][2];
            const float4 q3 = part[0][3];
            const float o0 = (q0.x + q1.x) + (q2.x + q3.x);
            const float o1 = (q0.y + q1.y) + (q2.y + q3.y);
            *(float2*)(pout + (size_t)(T - 1) * O) =
                make_float2(o0 * so0, o1 * so1);
        }
    }
}

// ---------------------------------------------------------------------------
extern "C" void kernel_launch(void* const* d_in, const int* in_sizes, int n_in,
                              void* d_out, int out_size, void* d_ws, size_t ws_size,
                              hipStream_t stream) {
    const float* input = (const float*)d_in[0];
    const float* noise = (const float*)d_in[1];
    const float* wi    = (const float*)d_in[2];
    const float* si    = (const float*)d_in[3];
    const float* m     = (const float*)d_in[4];
    const float* n     = (const float*)d_in[5];
    const float* wo    = (const float*)d_in[6];
    const float* so    = (const float*)d_in[7];
    const float* h0    = (const float*)d_in[8];

    float* out  = (float*)d_out;                       // (B,T,O) first
    float* traj = (float*)d_out + (size_t)B * T * O;   // then (B,T,H)

    (void)d_ws; (void)ws_size;

    // Single fully fused kernel: 64 blocks x 256 threads (4 waves/batch).
    rnn_fused4_kernel<<<B, 256, 0, stream>>>(input, noise, wi, si,
                                             m, n, wo, so, h0, out, traj);
}

// Round 7
// 570.517 us; speedup vs baseline: 1.0324x; 1.0324x over previous
//
#include <hip/hip_runtime.h>
#include <cstddef>

// Problem constants (match reference)
constexpr int B = 64, T = 1024, I = 8, H = 512, O = 2;
constexpr float ALPHA = 0.2f;
constexpr float NOISE_STD = 0.05f;

constexpr int C  = 8;       // steps per chunk
constexpr int NC = T / C;   // 128 chunks

// ---------------------------------------------------------------------------
// DPP wave-64 sum reduction: result (total of all 64 lanes) lands in lane 63.
// ---------------------------------------------------------------------------
template <int CTRL>
__device__ __forceinline__ float dpp_add(float x) {
    int y = __builtin_amdgcn_update_dpp(0, __float_as_int(x), CTRL, 0xF, 0xF, true);
    return x + __int_as_float(y);
}

__device__ __forceinline__ float wave_sum_to_lane63(float x) {
    x = dpp_add<0x111>(x);  // row_shr:1
    x = dpp_add<0x112>(x);  // row_shr:2
    x = dpp_add<0x114>(x);  // row_shr:4
    x = dpp_add<0x118>(x);  // row_shr:8   -> lane 15 of each row = row sum
    x = dpp_add<0x142>(x);  // row_bcast:15
    x = dpp_add<0x143>(x);  // row_bcast:31 -> lane 63 = full sum
    return x;
}

// Fast tanh: 1 - 2/(exp(2x)+1), via v_exp_f32 + v_rcp_f32.
__device__ __forceinline__ float fast_tanh(float x) {
    float z = __builtin_amdgcn_exp2f(x * 2.885390081777927f);  // e^(2x)
    return fmaf(-2.0f, __builtin_amdgcn_rcpf(z + 1.0f), 1.0f);
}

// ---------------------------------------------------------------------------
// R7: ZERO in-loop VMEM. Chunked execution, C=8 steps/chunk:
//   - noise: register double-buffer (nzA/nzB), each refilled as an 8-load
//     burst at the chunk boundary TWO chunks ahead of consumption (~2 chunks
//     = 7000+ cyc of slack; the compiler's vmcnt placement is trivially free).
//   - traj: h values accumulate in parity-static register arrays (hhA/hhB),
//     burst-stored (8 dwordx2) once per chunk at the boundary.
//   - out: per-step value written to a tiny LDS obuf by thread 63 (post-
//     barrier section); 8 threads bulk-store the chunk's window at the
//     boundary. Window for chunk starting t0 is out[t0-1 .. t0+C-2]
//     (out[t] uses pre-update r of step t+1); t<0 predicated off; out[T-1]
//     written by the epilogue.
// The steady-state timestep contains ONLY VALU + DPP + LDS + the raw
// lgkm-only barrier (R5 protocol, unchanged). If per-step time stays ~900
// cyc, the tax is compute/LDS/barrier latency, not VMEM — clean attribution.
//
// 2-chunk outer body keeps all register-array indexing compile-time static
// (rule: runtime-indexed reg arrays spill to scratch).
// ---------------------------------------------------------------------------
__global__ __launch_bounds__(256)
void rnn_chunk_kernel(const float* __restrict__ input,
                      const float* __restrict__ noise,
                      const float* __restrict__ wi,
                      const float* __restrict__ si,
                      const float* __restrict__ m,
                      const float* __restrict__ n,
                      const float* __restrict__ wo,
                      const float* __restrict__ so,
                      const float* __restrict__ h0,
                      float* __restrict__ out,    // (B,T,O)
                      float* __restrict__ traj)   // (B,T,H)
{
    const int b    = blockIdx.x;
    const int w    = threadIdx.x >> 6;
    const int lane = threadIdx.x & 63;
    const int j0   = w * 128 + 2 * lane;   // first of this lane's 2 units

    __shared__ float  xin[T * I];          // 32 KB: input[b], staged once
    __shared__ float4 part[2][4];          // [u&1][wave] = (pa0,pa1,po0,po1)
    __shared__ float2 obuf[C];             // per-chunk out values

    // ---- stage input[b] into LDS (coalesced float4) ----
    {
        const float4* src = (const float4*)(input + (size_t)b * T * I);
        float4*       dst = (float4*)xin;
#pragma unroll
        for (int i = 0; i < (T * I / 4) / 256; ++i)
            dst[threadIdx.x + 256 * i] = src[threadIdx.x + 256 * i];
    }
    __syncthreads();   // once, outside the hot loop

    constexpr float RS  = ALPHA / (float)H;
    constexpr float OMA = 1.0f - ALPHA;
    const float so0 = so[0] / (float)H;
    const float so1 = so[1] / (float)H;

    // per-lane coefficients for 2 adjacent units (rows 2j0..2j0+3, 16B aligned)
    const float4 mv = *(const float4*)(m + 2 * j0);
    const float4 nv = *(const float4*)(n + 2 * j0);
    const float4 wv = *(const float4*)(wo + 2 * j0);
    const float mm0[2] = {mv.x * RS, mv.z * RS};
    const float mm1[2] = {mv.y * RS, mv.w * RS};
    const float nn0[2] = {nv.x, nv.z};
    const float nn1[2] = {nv.y, nv.w};
    const float ww0[2] = {wv.x, wv.z};
    const float ww1[2] = {wv.y, wv.w};

    float wif[I][2];
#pragma unroll
    for (int i = 0; i < I; ++i) {
        wif[i][0] = wi[i * H + j0]     * si[i];
        wif[i][1] = wi[i * H + j0 + 1] * si[i];
    }

    const float2 h0v = *(const float2*)(h0 + j0);
    float h[2] = {h0v.x, h0v.y};
    float r[2] = {tanhf(h[0]), tanhf(h[1])};   // full precision, once

    const float* pn   = noise + (size_t)b * T * H + j0;
    float*       pt   = traj  + (size_t)b * T * H + j0;
    float*       pout = out   + (size_t)b * T * O;

    float2 nzA[C], nzB[C];    // noise double-buffer (parity-static)
    float2 hhA[C], hhB[C];    // traj store sources (parity-static)

    // ---- prologue: burst-issue chunk 0 -> nzA, chunk 1 -> nzB ----
#pragma unroll
    for (int u = 0; u < C; ++u) nzA[u] = *(const float2*)(pn + (size_t)u * H);
#pragma unroll
    for (int u = 0; u < C; ++u) nzB[u] = *(const float2*)(pn + (size_t)(C + u) * H);

    // ---- one timestep (NO VMEM inside) ----
    auto do_step = [&](const int t, const int u, const float2 nzv, float2& hslot) {
        // uniform broadcast read of this step's 8 input values
        const float4 xa = *(const float4*)(xin + t * I);
        const float4 xb = *(const float4*)(xin + t * I + 4);

        // rank-2 + output partials from current r
        float pa0 = fmaf(r[1], nn0[1], r[0] * nn0[0]);
        float pa1 = fmaf(r[1], nn1[1], r[0] * nn1[0]);
        float po0 = fmaf(r[1], ww0[1], r[0] * ww0[0]);
        float po1 = fmaf(r[1], ww1[1], r[0] * ww1[0]);

        // 4 interleaved DPP trees (independent -> latency overlaps)
        pa0 = wave_sum_to_lane63(pa0);
        pa1 = wave_sum_to_lane63(pa1);
        po0 = wave_sum_to_lane63(po0);
        po1 = wave_sum_to_lane63(po1);

        // input projection + d + (1-a)h, off the post-barrier critical path
        float acc0 = xa.x * wif[0][0], acc1 = xa.x * wif[0][1];
        acc0 = fmaf(xa.y, wif[1][0], acc0); acc1 = fmaf(xa.y, wif[1][1], acc1);
        acc0 = fmaf(xa.z, wif[2][0], acc0); acc1 = fmaf(xa.z, wif[2][1], acc1);
        acc0 = fmaf(xa.w, wif[3][0], acc0); acc1 = fmaf(xa.w, wif[3][1], acc1);
        acc0 = fmaf(xb.x, wif[4][0], acc0); acc1 = fmaf(xb.x, wif[4][1], acc1);
        acc0 = fmaf(xb.y, wif[5][0], acc0); acc1 = fmaf(xb.y, wif[5][1], acc1);
        acc0 = fmaf(xb.z, wif[6][0], acc0); acc1 = fmaf(xb.z, wif[6][1], acc1);
        acc0 = fmaf(xb.w, wif[7][0], acc0); acc1 = fmaf(xb.w, wif[7][1], acc1);
        const float dv0  = fmaf(NOISE_STD, nzv.x, ALPHA * acc0);
        const float dv1  = fmaf(NOISE_STD, nzv.y, ALPHA * acc1);
        const float pre0 = fmaf(h[0], OMA, dv0);
        const float pre1 = fmaf(h[1], OMA, dv1);

        if (lane == 63) part[u & 1][w] = make_float4(pa0, pa1, po0, po1);

        // raw barrier: LDS-visibility wait ONLY (nothing on vmcnt to drain)
        __builtin_amdgcn_sched_barrier(0);
        asm volatile("s_waitcnt lgkmcnt(0)" ::: "memory");
        __builtin_amdgcn_s_barrier();
        __builtin_amdgcn_sched_barrier(0);

        // broadcast-read the 4 wave partials
        const float4 q0 = part[u & 1][0];
        const float4 q1 = part[u & 1][1];
        const float4 q2 = part[u & 1][2];
        const float4 q3 = part[u & 1][3];
        const float a0 = (q0.x + q1.x) + (q2.x + q3.x);
        const float a1 = (q0.y + q1.y) + (q2.y + q3.y);

        // out value for t-1 -> LDS staging (stored at chunk boundary)
        if (threadIdx.x == 63) {
            const float o0 = (q0.z + q1.z) + (q2.z + q3.z);
            const float o1 = (q0.w + q1.w) + (q2.w + q3.w);
            obuf[u] = make_float2(o0 * so0, o1 * so1);
        }

        // state update + fast tanh (critical path: 2 fma + tanh)
        h[0] = fmaf(a1, mm1[0], fmaf(a0, mm0[0], pre0));
        h[1] = fmaf(a1, mm1[1], fmaf(a0, mm0[1], pre1));
        r[0] = fast_tanh(h[0]);
        r[1] = fast_tanh(h[1]);

        hslot = make_float2(h[0], h[1]);   // register stash, stored at boundary
    };

    // ---- chunk boundary: ALL global traffic happens here, burst-mode ----
    auto boundary = [&](const int t0, float2 (&nz)[C], float2 (&hh)[C]) {
        // refill nz with chunk (t0/C + 2): consumed 2 chunks (~7000 cyc) later
#pragma unroll
        for (int u = 0; u < C; ++u) {
            const int tl = t0 + 2 * C + u;
            const int tc = (tl < T) ? tl : (T - 1);   // uniform clamp
            nz[u] = *(const float2*)(pn + (size_t)tc * H);
        }
        // traj burst-store for the chunk just computed
#pragma unroll
        for (int u = 0; u < C; ++u)
            *(float2*)(pt + (size_t)(t0 + u) * H) = hh[u];

        // make obuf visible, then 8 threads store out[t0-1 .. t0+C-2]
        __builtin_amdgcn_sched_barrier(0);
        asm volatile("s_waitcnt lgkmcnt(0)" ::: "memory");
        __builtin_amdgcn_s_barrier();
        __builtin_amdgcn_sched_barrier(0);
        if (threadIdx.x < C) {
            const float2 ov = obuf[threadIdx.x];
            const int    t  = t0 + (int)threadIdx.x - 1;
            if (t >= 0) *(float2*)(pout + (size_t)t * O) = ov;
        }
    };

    static_assert(NC % 2 == 0, "chunk count must be even");

#pragma unroll 1
    for (int tc = 0; tc < NC; tc += 2) {
        const int base0 = tc * C;
        const int base1 = base0 + C;

#pragma unroll
        for (int u = 0; u < C; ++u) do_step(base0 + u, u, nzA[u], hhA[u]);
        boundary(base0, nzA, hhA);

#pragma unroll
        for (int u = 0; u < C; ++u) do_step(base1 + u, u, nzB[u], hhB[u]);
        boundary(base1, nzB, hhB);
    }

    // ---- final output for t = T-1 (uses post-update r) ----
    {
        float po0 = fmaf(r[1], ww0[1], r[0] * ww0[0]);
        float po1 = fmaf(r[1], ww1[1], r[0] * ww1[0]);
        po0 = wave_sum_to_lane63(po0);
        po1 = wave_sum_to_lane63(po1);
        if (lane == 63) part[0][w] = make_float4(po0, po1, 0.f, 0.f);
        __syncthreads();
        if (threadIdx.x == 63) {
            const float4 q0 = part[0][0];
            const float4 q1 = part[0][1];
            const float4 q2 = part[0][2];
            const float4 q3 = part[0][3];
            const float o0 = (q0.x + q1.x) + (q2.x + q3.x);
            const float o1 = (q0.y + q1.y) + (q2.y + q3.y);
            *(float2*)(pout + (size_t)(T - 1) * O) =
                make_float2(o0 * so0, o1 * so1);
        }
    }
}

// ---------------------------------------------------------------------------
extern "C" void kernel_launch(void* const* d_in, const int* in_sizes, int n_in,
                              void* d_out, int out_size, void* d_ws, size_t ws_size,
                              hipStream_t stream) {
    const float* input = (const float*)d_in[0];
    const float* noise = (const float*)d_in[1];
    const float* wi    = (const float*)d_in[2];
    const float* si    = (const float*)d_in[3];
    const float* m     = (const float*)d_in[4];
    const float* n     = (const float*)d_in[5];
    const float* wo    = (const float*)d_in[6];
    const float* so    = (const float*)d_in[7];
    const float* h0    = (const float*)d_in[8];

    float* out  = (float*)d_out;                       // (B,T,O) first
    float* traj = (float*)d_out + (size_t)B * T * O;   // then (B,T,H)

    (void)d_ws; (void)ws_size;

    // Single fused kernel: 64 blocks x 256 threads (4 waves/batch).
    rnn_chunk_kernel<<<B, 256, 0, stream>>>(input, noise, wi, si,
                                            m, n, wo, so, h0, out, traj);
}